// Round 5
// baseline (349.273 us; speedup 1.0000x reference)
//
#include <hip/hip_runtime.h>
#include <hip/hip_bf16.h>

#define NQ 65536
#define DIM 512
#define HID 256
#define NWAY 5
#define NKPTS 17

typedef short bf16x8 __attribute__((ext_vector_type(8)));
typedef float f32x4 __attribute__((ext_vector_type(4)));
typedef _Float16 half8 __attribute__((ext_vector_type(8)));

static __device__ __forceinline__ unsigned short f2bf(float f) {
    unsigned int x = __float_as_uint(f);
    unsigned int r = (x + 0x7fffu + ((x >> 16) & 1u)) >> 16;
    return (unsigned short)r;
}

static __device__ __forceinline__ void async16(void* l, const void* g) {
    __builtin_amdgcn_global_load_lds(
        (const __attribute__((address_space(1))) unsigned int*)g,
        (__attribute__((address_space(3))) unsigned int*)l, 16, 0, 0);
}

// ---------------- support layer 1: ws_h1 = relu(sf@W1+b1), coalesced over columns ----------
__global__ __launch_bounds__(256) void k_sup(const float* __restrict__ sf,
                                             const float* __restrict__ W1, const float* __restrict__ b1,
                                             float* __restrict__ ws_h1) {
    __shared__ float sfl[512];
    __shared__ float red[4][64];
    int bx = blockIdx.x;
    int s = bx >> 3, cb = bx & 7;
    int t = threadIdx.x;
    if (t < 128) ((float4*)sfl)[t] = ((const float4*)(sf + s * DIM))[t];
    __syncthreads();
    int c = cb * 64 + (t & 63);
    int qd = t >> 6;                 // k-quarter 0..3 (wave-uniform)
    const float* Wp = W1 + (size_t)qd * 128 * DIM + c;
    float acc = 0.0f;
    #pragma unroll 4
    for (int kk = 0; kk < 128; kk++)
        acc += sfl[qd * 128 + kk] * Wp[(size_t)kk * DIM];
    red[qd][t & 63] = acc;
    __syncthreads();
    if (t < 64) {
        float h = red[0][t] + red[1][t] + red[2][t] + red[3][t] + b1[cb * 64 + t];
        ws_h1[s * DIM + cb * 64 + t] = fmaxf(h, 0.0f);
    }
}

// ---------------- k_mid2: prototypes (mean then W2, coalesced) + [Wo1|Wc1] transpose->bf16 ----
__global__ __launch_bounds__(256) void k_mid2(const float* __restrict__ ws_h1,
                                              const float* __restrict__ W2, const float* __restrict__ b2,
                                              const float* __restrict__ Wo1, const float* __restrict__ Wc1,
                                              float* __restrict__ ws_proto, unsigned short* __restrict__ wb) {
    int bx = blockIdx.x;
    int t = threadIdx.x;
    if (bx < 40) {
        __shared__ float ml[512];
        __shared__ float red[4][64];
        int w = bx >> 3, cb = bx & 7;
        for (int i = t; i < 512; i += 256) {
            float sum = 0.0f;
            #pragma unroll
            for (int s5 = 0; s5 < 5; s5++) sum += ws_h1[(w * 5 + s5) * DIM + i];
            ml[i] = sum * 0.2f;
        }
        __syncthreads();
        int c = cb * 64 + (t & 63);
        int qd = t >> 6;
        const float* Wp = W2 + (size_t)qd * 128 * DIM + c;
        float acc = 0.0f;
        #pragma unroll 4
        for (int kk = 0; kk < 128; kk++)
            acc += ml[qd * 128 + kk] * Wp[(size_t)kk * DIM];
        red[qd][t & 63] = acc;
        __syncthreads();
        if (t < 64)
            ws_proto[w * DIM + cb * 64 + t] =
                red[0][t] + red[1][t] + red[2][t] + red[3][t] + b2[cb * 64 + t];
    } else {
        __shared__ unsigned short T[64][72];
        int tb = bx - 40;                    // 0..63
        const float* src = (tb < 32) ? Wo1 : Wc1;
        int cofs = (tb < 32) ? 0 : 256;
        int tt = tb & 31;
        int kt = tt >> 2;                    // k-tile 0..7
        int ct = tt & 3;                     // c-tile 0..3
        int i = t >> 2;                      // k row within tile 0..63
        int qd = t & 3;
        const float* rp = src + (size_t)(kt * 64 + i) * HID + ct * 64 + qd * 16;
        #pragma unroll
        for (int v = 0; v < 4; v++) {
            float4 x = *(const float4*)(rp + v * 4);
            T[qd * 16 + v * 4 + 0][i] = f2bf(x.x);
            T[qd * 16 + v * 4 + 1][i] = f2bf(x.y);
            T[qd * 16 + v * 4 + 2][i] = f2bf(x.z);
            T[qd * 16 + v * 4 + 3][i] = f2bf(x.w);
        }
        __syncthreads();
        int j = t >> 2;                      // c within tile
        int part = t & 3;
        uint4 o0 = *(const uint4*)&T[j][part * 16];
        uint4 o1 = *(const uint4*)&T[j][part * 16 + 8];
        unsigned short* dst = wb + (size_t)(cofs + ct * 64 + j) * DIM + kt * 64 + part * 16;
        *(uint4*)dst = o0;
        *(uint4*)(dst + 8) = o1;
    }
}

// ---------------- k_dist: distances/argmin, lane=(query,k-quarter), 0.75 shfl/query --------
// block = 256 thr = 4 waves; each wave: 16 queries, lane (l&15)=query, (l>>4)=k-quarter(128).
// proto read from global (L1-broadcast: 4 unique addrs/instr). qf expected L3-resident.
__global__ __launch_bounds__(256) void k_dist(const float* __restrict__ qf,
                                              const float* __restrict__ ws_proto,
                                              const float* __restrict__ temp_p,
                                              float* __restrict__ out_dist, float* __restrict__ out_class,
                                              float* __restrict__ out_proto) {
    __shared__ float pn_lds[8];
    __shared__ float dlds[64 * NWAY];
    int bx = blockIdx.x, t = threadIdx.x;
    int wv = t >> 6, lane = t & 63;

    // out_proto broadcast (first 85 blocks)
    if (bx < NWAY * NKPTS && t < 128) {
        f32x4 v = *(const f32x4*)(ws_proto + (bx / NKPTS) * DIM + t * 4);
        *(f32x4*)(out_proto + (size_t)bx * DIM + t * 4) = v;
    }
    // proto norms: wave wv handles ways wv, wv+4
    for (int w = wv; w < NWAY; w += 4) {
        f32x4 a = *(const f32x4*)(ws_proto + w * DIM + lane * 8);
        f32x4 b = *(const f32x4*)(ws_proto + w * DIM + lane * 8 + 4);
        float ss = a[0]*a[0] + a[1]*a[1] + a[2]*a[2] + a[3]*a[3]
                 + b[0]*b[0] + b[1]*b[1] + b[2]*b[2] + b[3]*b[3];
        #pragma unroll
        for (int off = 32; off > 0; off >>= 1) ss += __shfl_xor(ss, off, 64);
        if (lane == 0) pn_lds[w] = sqrtf(ss);
    }
    float invt = 1.0f / temp_p[0];
    __syncthreads();

    int q = bx * 64 + wv * 16 + (lane & 15);
    int kq = (lane >> 4) * 128;
    const float* qp = qf + (size_t)q * DIM + kq;
    const float* pp = ws_proto + kq;

    float ds[NWAY] = {0, 0, 0, 0, 0};
    float qq = 0.0f;
    #pragma unroll 4
    for (int c = 0; c < 16; c++) {
        f32x4 v0 = *(const f32x4*)(qp + c * 8);
        f32x4 v1 = *(const f32x4*)(qp + c * 8 + 4);
        qq += v0[0]*v0[0] + v0[1]*v0[1] + v0[2]*v0[2] + v0[3]*v0[3]
            + v1[0]*v1[0] + v1[1]*v1[1] + v1[2]*v1[2] + v1[3]*v1[3];
        #pragma unroll
        for (int w = 0; w < NWAY; w++) {
            f32x4 p0 = *(const f32x4*)(pp + w * DIM + c * 8);
            f32x4 p1 = *(const f32x4*)(pp + w * DIM + c * 8 + 4);
            ds[w] += v0[0]*p0[0] + v0[1]*p0[1] + v0[2]*p0[2] + v0[3]*p0[3]
                   + v1[0]*p1[0] + v1[1]*p1[1] + v1[2]*p1[2] + v1[3]*p1[3];
        }
    }
    // reduce over the 4 k-quarters: lanes l, l^16, l^32
    #pragma unroll
    for (int off = 16; off <= 32; off <<= 1) {
        #pragma unroll
        for (int w = 0; w < NWAY; w++) ds[w] += __shfl_xor(ds[w], off, 64);
        qq += __shfl_xor(qq, off, 64);
    }
    if (lane < 16) {
        float qn = sqrtf(qq);
        float mv = 1e30f; int ami = 0;
        #pragma unroll
        for (int w = 0; w < NWAY; w++) {
            float den = fmaxf(qn * pn_lds[w], 1e-8f);
            float d = (1.0f - ds[w] / den) * invt;
            dlds[(wv * 16 + lane) * NWAY + w] = d;
            if (d < mv) { mv = d; ami = w; }
        }
        out_class[q] = (float)ami;
    }
    __syncthreads();
    int Q0 = bx * 64;
    for (int i = t; i < 64 * NWAY * NKPTS; i += 256) {
        int q2 = i / (NWAY * NKPTS);
        int rem = i - q2 * (NWAY * NKPTS);
        out_dist[(size_t)(Q0 + q2) * (NWAY * NKPTS) + rem] = dlds[q2 * NWAY + rem / NKPTS];
    }
}

// ---------------- k_gemm: 64x256 tile, 4 waves (1Mx4N, wave 64x64), acc=64 regs ------------
// BK=32, 16 steps. A f32->bf16 reg-staged dbuf; B global_load_lds dbuf; counted-vmcnt
// barriers (prefetches stay in flight). 8-row XOR swizzle -> ~2-way LDS (free).
// grid 2048: mb = bx & 1023, head nb = bx >> 10. 3 blocks/CU (12 waves).
__global__ __launch_bounds__(256, 3) void k_gemm(const float* __restrict__ qf,
                                                 const unsigned short* __restrict__ wb,
                                                 const float* __restrict__ bo1, const float* __restrict__ Wo2,
                                                 const float* __restrict__ bo2,
                                                 const float* __restrict__ bc1, const float* __restrict__ Wc2,
                                                 const float* __restrict__ bc2,
                                                 const float* __restrict__ ic,
                                                 float* __restrict__ out_kp, float* __restrict__ out_conf) {
    __shared__ __align__(16) char smem[40960];
    char* Ab = smem;                          // 2 x [64 rows][64B]  = 8192
    char* Bb = smem + 8192;                   // 2 x [256 cols][64B] = 32768
    _Float16* hl = (_Float16*)smem;           // epilogue [64][264] f16 = 33792
    float* redf = (float*)(smem + 33792);     // epilogue partials 2KB

    int bx = blockIdx.x;
    int mb = bx & 1023, nb = bx >> 10;
    int t = threadIdx.x;
    int wv = t >> 6, lane = t & 63;
    int r = lane & 15, hq = lane >> 4;

    // A staging: thread owns (row am, k-chunk akc); swizzled slot = akc ^ (am&3) ^ ((am>>2)&1)
    int am = t >> 2, akc = t & 3;
    const float* Ag = qf + ((size_t)mb * 64 + am) * DIM + akc * 8;
    int awoff = am * 64 + ((akc ^ (am & 3) ^ ((am >> 2) & 1)) << 4);

    // B staging: per wave 4 chunks of 16 cols; source k-slot pre-swizzled (rule 21)
    int srow = lane >> 2;
    int sg = (lane & 3) ^ (srow & 3) ^ ((srow >> 2) & 1);
    const unsigned short* Bg = wb + (size_t)(nb * 256 + wv * 64 + srow) * DIM + sg * 8;

    f32x4 acc[4][4];
    #pragma unroll
    for (int i2 = 0; i2 < 4; i2++)
        #pragma unroll
        for (int j2 = 0; j2 < 4; j2++) { f32x4 z = {0.0f, 0.0f, 0.0f, 0.0f}; acc[i2][j2] = z; }

    // prologue: a(0) -> regs, B(0) -> LDS p0, a(1) -> regs; stage A(0)
    float4 aW0 = *(const float4*)(Ag);
    float4 aW1 = *(const float4*)(Ag + 4);
    #pragma unroll
    for (int i = 0; i < 4; i++)
        async16(Bb + wv * 4096 + i * 1024, Bg + (size_t)i * 16 * DIM);
    float4 aN0 = *(const float4*)(Ag + 32);
    float4 aN1 = *(const float4*)(Ag + 36);
    {
        unsigned int p0 = f2bf(aW0.x) | ((unsigned int)f2bf(aW0.y) << 16);
        unsigned int p1 = f2bf(aW0.z) | ((unsigned int)f2bf(aW0.w) << 16);
        unsigned int p2 = f2bf(aW1.x) | ((unsigned int)f2bf(aW1.y) << 16);
        unsigned int p3 = f2bf(aW1.z) | ((unsigned int)f2bf(aW1.w) << 16);
        *(uint4*)(Ab + awoff) = make_uint4(p0, p1, p2, p3);
    }
    aW0 = aN0; aW1 = aN1;
    asm volatile("s_waitcnt lgkmcnt(0) vmcnt(2)" ::: "memory");   // B(0) landed; a(1) in flight
    __builtin_amdgcn_s_barrier();
    __builtin_amdgcn_sched_barrier(0);

    int slot8 = (hq ^ (r & 3) ^ ((r >> 2) & 1)) * 8;   // swizzled 16B k-slot (shorts)

    for (int it = 0; it < 15; it++) {
        int par = it & 1;
        // issue B(it+1) into other parity
        #pragma unroll
        for (int i = 0; i < 4; i++)
            async16(Bb + (par ^ 1) * 16384 + wv * 4096 + i * 1024,
                    Bg + (size_t)i * 16 * DIM + (it + 1) * 32);
        // issue a(it+2)
        float4 aL0, aL1;
        if (it < 14) {
            aL0 = *(const float4*)(Ag + (it + 2) * 32);
            aL1 = *(const float4*)(Ag + (it + 2) * 32 + 4);
        }
        // stage A(it+1) from aW (loaded one iter ago)
        {
            unsigned int p0 = f2bf(aW0.x) | ((unsigned int)f2bf(aW0.y) << 16);
            unsigned int p1 = f2bf(aW0.z) | ((unsigned int)f2bf(aW0.w) << 16);
            unsigned int p2 = f2bf(aW1.x) | ((unsigned int)f2bf(aW1.y) << 16);
            unsigned int p3 = f2bf(aW1.z) | ((unsigned int)f2bf(aW1.w) << 16);
            *(uint4*)(Ab + (par ^ 1) * 4096 + awoff) = make_uint4(p0, p1, p2, p3);
        }
        // fragments + MFMA on tile it
        const unsigned short* Ap = (const unsigned short*)(Ab + par * 4096);
        const unsigned short* Bp = (const unsigned short*)(Bb + par * 16384);
        bf16x8 af[4], bfr[4];
        #pragma unroll
        for (int mt = 0; mt < 4; mt++)
            af[mt] = *(const bf16x8*)(Ap + (mt * 16 + r) * 32 + slot8);
        #pragma unroll
        for (int nt = 0; nt < 4; nt++)
            bfr[nt] = *(const bf16x8*)(Bp + (wv * 64 + nt * 16 + r) * 32 + slot8);
        #pragma unroll
        for (int mt = 0; mt < 4; mt++)
            #pragma unroll
            for (int nt = 0; nt < 4; nt++)
                acc[mt][nt] = __builtin_amdgcn_mfma_f32_16x16x32_bf16(af[mt], bfr[nt], acc[mt][nt], 0, 0, 0);
        // counted barrier: B(it+1) must land; a(it+2) stays in flight
        if (it < 14) { asm volatile("s_waitcnt lgkmcnt(0) vmcnt(2)" ::: "memory"); }
        else         { asm volatile("s_waitcnt lgkmcnt(0) vmcnt(0)" ::: "memory"); }
        __builtin_amdgcn_s_barrier();
        __builtin_amdgcn_sched_barrier(0);
        if (it < 14) { aW0 = aL0; aW1 = aL1; }
    }
    // final K-step (it = 15, parity 1)
    {
        const unsigned short* Ap = (const unsigned short*)(Ab + 4096);
        const unsigned short* Bp = (const unsigned short*)(Bb + 16384);
        bf16x8 af[4], bfr[4];
        #pragma unroll
        for (int mt = 0; mt < 4; mt++)
            af[mt] = *(const bf16x8*)(Ap + (mt * 16 + r) * 32 + slot8);
        #pragma unroll
        for (int nt = 0; nt < 4; nt++)
            bfr[nt] = *(const bf16x8*)(Bp + (wv * 64 + nt * 16 + r) * 32 + slot8);
        #pragma unroll
        for (int mt = 0; mt < 4; mt++)
            #pragma unroll
            for (int nt = 0; nt < 4; nt++)
                acc[mt][nt] = __builtin_amdgcn_mfma_f32_16x16x32_bf16(af[mt], bfr[nt], acc[mt][nt], 0, 0, 0);
    }
    __syncthreads();   // pipeline LDS dead -> hl reuse safe

    // ---- epilogue: bias + relu -> f16 LDS [64][264] ----
    const float* bias = nb ? bc1 : bo1;
    #pragma unroll
    for (int nt = 0; nt < 4; nt++) {
        int cl = wv * 64 + nt * 16 + r;
        float bv = bias[cl];
        #pragma unroll
        for (int mt = 0; mt < 4; mt++)
            #pragma unroll
            for (int rg = 0; rg < 4; rg++) {
                int ml = mt * 16 + hq * 4 + rg;
                hl[ml * 264 + cl] = (_Float16)fmaxf(acc[mt][nt][rg] + bv, 0.0f);
            }
    }
    __syncthreads();

    int q = t & 63, qt = t >> 6;    // qt: 64-col quarter (wave-uniform)
    if (nb == 0) {
        float ox = 0.0f, oy = 0.0f;
        #pragma unroll 2
        for (int j0 = 0; j0 < 64; j0 += 8) {
            half8 hv = *(const half8*)(hl + q * 264 + qt * 64 + j0);
            #pragma unroll
            for (int j = 0; j < 8; j++) {
                float2 w2 = *(const float2*)(Wo2 + (qt * 64 + j0 + j) * 2);
                float hf = (float)hv[j];
                ox += hf * w2.x;
                oy += hf * w2.y;
            }
        }
        redf[(qt * 64 + q) * 2] = ox;
        redf[(qt * 64 + q) * 2 + 1] = oy;
        __syncthreads();
        if (t < 64) {
            float sx = bo2[0], sy = bo2[1];
            #pragma unroll
            for (int k2 = 0; k2 < 4; k2++) {
                sx += redf[(k2 * 64 + t) * 2];
                sy += redf[(k2 * 64 + t) * 2 + 1];
            }
            size_t Q = (size_t)mb * 64 + t;
            float2 icv = *(const float2*)(ic + Q * 2);
            float gx = icv.x / (1.0f + __expf(-sx));
            float gy = icv.y / (1.0f + __expf(-sy));
            float2 g2 = make_float2(gx, gy);
            float2* dst = (float2*)(out_kp + Q * 34);
            #pragma unroll
            for (int k2 = 0; k2 < 17; k2++) dst[k2] = g2;
        }
    } else {
        float cs = 0.0f;
        #pragma unroll 2
        for (int j0 = 0; j0 < 64; j0 += 8) {
            half8 hv = *(const half8*)(hl + q * 264 + qt * 64 + j0);
            #pragma unroll
            for (int j = 0; j < 8; j++)
                cs += (float)hv[j] * Wc2[qt * 64 + j0 + j];
        }
        redf[qt * 64 + q] = cs;
        __syncthreads();
        if (t < 64) {
            float s = bc2[0] + redf[t] + redf[64 + t] + redf[128 + t] + redf[192 + t];
            float sg2 = 1.0f / (1.0f + __expf(-s));
            size_t Q = (size_t)mb * 64 + t;
            float* dst = out_conf + Q * 17;
            #pragma unroll
            for (int k2 = 0; k2 < 17; k2++) dst[k2] = sg2;
        }
    }
}

extern "C" void kernel_launch(void* const* d_in, const int* in_sizes, int n_in,
                              void* d_out, int out_size, void* d_ws, size_t ws_size,
                              hipStream_t stream) {
    const float* sf = (const float*)d_in[0];
    const float* qf = (const float*)d_in[2];
    const float* ic = (const float*)d_in[3];
    const float* W1 = (const float*)d_in[4];
    const float* b1 = (const float*)d_in[5];
    const float* W2 = (const float*)d_in[6];
    const float* b2 = (const float*)d_in[7];
    const float* Wo1 = (const float*)d_in[8];
    const float* bo1 = (const float*)d_in[9];
    const float* Wo2 = (const float*)d_in[10];
    const float* bo2 = (const float*)d_in[11];
    const float* Wc1 = (const float*)d_in[12];
    const float* bc1 = (const float*)d_in[13];
    const float* Wc2 = (const float*)d_in[14];
    const float* bc2 = (const float*)d_in[15];
    const float* temp = (const float*)d_in[16];

    float* out = (float*)d_out;
    float* out_kp = out;                   // 65536*17*2
    float* out_conf = out + 2228224;       // 65536*17
    float* out_dist = out + 3342336;       // 65536*5*17
    float* out_class = out + 8912896;      // 65536
    float* out_proto = out + 8978432;      // 5*17*512

    char* ws = (char*)d_ws;
    float* ws_h1 = (float*)ws;                               // 25*512 f32
    float* ws_proto = (float*)(ws + 51200);                  // 5*512 f32
    unsigned short* ws_wb = (unsigned short*)(ws + 65536);   // 512*512 bf16 (transposed [Wo1|Wc1])

    hipLaunchKernelGGL(k_sup, dim3(200), dim3(256), 0, stream, sf, W1, b1, ws_h1);
    hipLaunchKernelGGL(k_mid2, dim3(104), dim3(256), 0, stream, ws_h1, W2, b2, Wo1, Wc1, ws_proto, ws_wb);
    hipLaunchKernelGGL(k_dist, dim3(1024), dim3(256), 0, stream, qf, ws_proto, temp,
                       out_dist, out_class, out_proto);
    hipLaunchKernelGGL(k_gemm, dim3(2048), dim3(256), 0, stream, qf, ws_wb,
                       bo1, Wo2, bo2, bc1, Wc2, bc2, ic, out_kp, out_conf);
}

// Round 6
// 327.686 us; speedup vs baseline: 1.0659x; 1.0659x over previous
//
#include <hip/hip_runtime.h>
#include <hip/hip_bf16.h>

#define NQ 65536
#define DIM 512
#define HID 256
#define NWAY 5
#define NKPTS 17

typedef short bf16x8 __attribute__((ext_vector_type(8)));
typedef float f32x4 __attribute__((ext_vector_type(4)));
typedef _Float16 half8 __attribute__((ext_vector_type(8)));

static __device__ __forceinline__ unsigned short f2bf(float f) {
    unsigned int x = __float_as_uint(f);
    unsigned int r = (x + 0x7fffu + ((x >> 16) & 1u)) >> 16;
    return (unsigned short)r;
}

static __device__ __forceinline__ void async16(void* l, const void* g) {
    __builtin_amdgcn_global_load_lds(
        (const __attribute__((address_space(1))) unsigned int*)g,
        (__attribute__((address_space(3))) unsigned int*)l, 16, 0, 0);
}

// ---------------- support layer 1: ws_h1 = relu(sf@W1+b1), coalesced over columns ----------
__global__ __launch_bounds__(256) void k_sup(const float* __restrict__ sf,
                                             const float* __restrict__ W1, const float* __restrict__ b1,
                                             float* __restrict__ ws_h1) {
    __shared__ float sfl[512];
    __shared__ float red[4][64];
    int bx = blockIdx.x;
    int s = bx >> 3, cb = bx & 7;
    int t = threadIdx.x;
    if (t < 128) ((float4*)sfl)[t] = ((const float4*)(sf + s * DIM))[t];
    __syncthreads();
    int c = cb * 64 + (t & 63);
    int qd = t >> 6;                 // k-quarter 0..3 (wave-uniform)
    const float* Wp = W1 + (size_t)qd * 128 * DIM + c;
    float acc = 0.0f;
    #pragma unroll 4
    for (int kk = 0; kk < 128; kk++)
        acc += sfl[qd * 128 + kk] * Wp[(size_t)kk * DIM];
    red[qd][t & 63] = acc;
    __syncthreads();
    if (t < 64) {
        float h = red[0][t] + red[1][t] + red[2][t] + red[3][t] + b1[cb * 64 + t];
        ws_h1[s * DIM + cb * 64 + t] = fmaxf(h, 0.0f);
    }
}

// ---------------- k_mid2: prototypes (mean then W2, coalesced) + [Wo1|Wc1] transpose->bf16 ----
__global__ __launch_bounds__(256) void k_mid2(const float* __restrict__ ws_h1,
                                              const float* __restrict__ W2, const float* __restrict__ b2,
                                              const float* __restrict__ Wo1, const float* __restrict__ Wc1,
                                              float* __restrict__ ws_proto, unsigned short* __restrict__ wb) {
    int bx = blockIdx.x;
    int t = threadIdx.x;
    if (bx < 40) {
        __shared__ float ml[512];
        __shared__ float red[4][64];
        int w = bx >> 3, cb = bx & 7;
        for (int i = t; i < 512; i += 256) {
            float sum = 0.0f;
            #pragma unroll
            for (int s5 = 0; s5 < 5; s5++) sum += ws_h1[(w * 5 + s5) * DIM + i];
            ml[i] = sum * 0.2f;
        }
        __syncthreads();
        int c = cb * 64 + (t & 63);
        int qd = t >> 6;
        const float* Wp = W2 + (size_t)qd * 128 * DIM + c;
        float acc = 0.0f;
        #pragma unroll 4
        for (int kk = 0; kk < 128; kk++)
            acc += ml[qd * 128 + kk] * Wp[(size_t)kk * DIM];
        red[qd][t & 63] = acc;
        __syncthreads();
        if (t < 64)
            ws_proto[w * DIM + cb * 64 + t] =
                red[0][t] + red[1][t] + red[2][t] + red[3][t] + b2[cb * 64 + t];
    } else {
        __shared__ unsigned short T[64][72];
        int tb = bx - 40;                    // 0..63
        const float* src = (tb < 32) ? Wo1 : Wc1;
        int cofs = (tb < 32) ? 0 : 256;
        int tt = tb & 31;
        int kt = tt >> 2;                    // k-tile 0..7
        int ct = tt & 3;                     // c-tile 0..3
        int i = t >> 2;                      // k row within tile 0..63
        int qd = t & 3;
        const float* rp = src + (size_t)(kt * 64 + i) * HID + ct * 64 + qd * 16;
        #pragma unroll
        for (int v = 0; v < 4; v++) {
            float4 x = *(const float4*)(rp + v * 4);
            T[qd * 16 + v * 4 + 0][i] = f2bf(x.x);
            T[qd * 16 + v * 4 + 1][i] = f2bf(x.y);
            T[qd * 16 + v * 4 + 2][i] = f2bf(x.z);
            T[qd * 16 + v * 4 + 3][i] = f2bf(x.w);
        }
        __syncthreads();
        int j = t >> 2;                      // c within tile
        int part = t & 3;
        uint4 o0 = *(const uint4*)&T[j][part * 16];
        uint4 o1 = *(const uint4*)&T[j][part * 16 + 8];
        unsigned short* dst = wb + (size_t)(cofs + ct * 64 + j) * DIM + kt * 64 + part * 16;
        *(uint4*)dst = o0;
        *(uint4*)(dst + 8) = o1;
    }
}

// ---------------- k_gemm2: 64x256 tile MFMA + (nb==1) fused f32 distances ------------------
// 4 waves (1Mx4N, wave 64x64), BK=32, counted-vmcnt dbuf pipeline (round-5 verified).
// grid 2048: nb = bx&1 (head), mb = bx>>1 (row tile) -> heads interleave across CUs.
// nb==1 blocks additionally: s_proto in LDS, dist partials from the f32 A-staging regs
// (round-4 summation order), dist/class/proto outputs in the epilogue.
__global__ __launch_bounds__(256, 3) void k_gemm2(const float* __restrict__ qf,
                                                  const unsigned short* __restrict__ wb,
                                                  const float* __restrict__ ws_proto,
                                                  const float* __restrict__ temp_p,
                                                  const float* __restrict__ bo1, const float* __restrict__ Wo2,
                                                  const float* __restrict__ bo2,
                                                  const float* __restrict__ bc1, const float* __restrict__ Wc2,
                                                  const float* __restrict__ bc2,
                                                  const float* __restrict__ ic,
                                                  float* __restrict__ out_kp, float* __restrict__ out_conf,
                                                  float* __restrict__ out_dist, float* __restrict__ out_class,
                                                  float* __restrict__ out_proto) {
    __shared__ __align__(16) char smem[52512];
    char* Ab = smem;                          // 2 x [64 rows][64B]  = 8192      [0,8192)
    char* Bb = smem + 8192;                   // 2 x [256 cols][64B] = 32768     [8192,40960)
    float* s_proto = (float*)(smem + 40960);  // 5*512 f32                       [40960,51200)
    float* pn_lds = (float*)(smem + 51200);   // 8 f32
    float* dlds = (float*)(smem + 51232);     // 64*5 f32                        [51232,52512)
    _Float16* hl = (_Float16*)smem;           // epilogue [64][264] f16 = 33792  [0,33792)
    float* redf = (float*)(smem + 33792);     // epilogue partials 2KB           [33792,35840)

    int bx = blockIdx.x;
    int nb = bx & 1, mb = bx >> 1;
    int t = threadIdx.x;
    int wv = t >> 6, lane = t & 63;
    int r = lane & 15, hq = lane >> 4;

    // A staging: thread owns (row am, k-chunk akc); swizzled slot = akc ^ (am&3) ^ ((am>>2)&1)
    int am = t >> 2, akc = t & 3;
    const float* Ag = qf + ((size_t)mb * 64 + am) * DIM + akc * 8;
    int awoff = am * 64 + ((akc ^ (am & 3) ^ ((am >> 2) & 1)) << 4);

    // B staging: per wave 4 chunks of 16 cols; source k-slot pre-swizzled (rule 21)
    int srow = lane >> 2;
    int sg = (lane & 3) ^ (srow & 3) ^ ((srow >> 2) & 1);
    const unsigned short* Bg = wb + (size_t)(nb * 256 + wv * 64 + srow) * DIM + sg * 8;

    f32x4 acc[4][4];
    #pragma unroll
    for (int i2 = 0; i2 < 4; i2++)
        #pragma unroll
        for (int j2 = 0; j2 < 4; j2++) { f32x4 z = {0.0f, 0.0f, 0.0f, 0.0f}; acc[i2][j2] = z; }
    float ds[NWAY] = {0, 0, 0, 0, 0};
    float qq = 0.0f;
    float invt = 0.0f;

    // nb==1 prologue: proto -> LDS; out_proto broadcast (first 85 row-tiles); temp
    if (nb) {
        for (int i = t; i < NWAY * DIM; i += 256) s_proto[i] = ws_proto[i];
        if (mb < NWAY * NKPTS && t < 128) {
            f32x4 v = *(const f32x4*)(ws_proto + (mb / NKPTS) * DIM + t * 4);
            *(f32x4*)(out_proto + (size_t)mb * DIM + t * 4) = v;
        }
        invt = 1.0f / temp_p[0];
    }

    // prologue: a(0) -> regs, B(0) -> LDS p0, a(1) -> regs; stage A(0)
    float4 aW0 = *(const float4*)(Ag);
    float4 aW1 = *(const float4*)(Ag + 4);
    #pragma unroll
    for (int i = 0; i < 4; i++)
        async16(Bb + wv * 4096 + i * 1024, Bg + (size_t)i * 16 * DIM);
    float4 aN0 = *(const float4*)(Ag + 32);
    float4 aN1 = *(const float4*)(Ag + 36);
    {
        unsigned int p0 = f2bf(aW0.x) | ((unsigned int)f2bf(aW0.y) << 16);
        unsigned int p1 = f2bf(aW0.z) | ((unsigned int)f2bf(aW0.w) << 16);
        unsigned int p2 = f2bf(aW1.x) | ((unsigned int)f2bf(aW1.y) << 16);
        unsigned int p3 = f2bf(aW1.z) | ((unsigned int)f2bf(aW1.w) << 16);
        *(uint4*)(Ab + awoff) = make_uint4(p0, p1, p2, p3);
    }
    float4 c0 = aW0, c1 = aW1;     // keep a(0) f32 values for dist window 0
    aW0 = aN0; aW1 = aN1;
    asm volatile("s_waitcnt lgkmcnt(0) vmcnt(2)" ::: "memory");   // B(0)+s_proto landed; a(1) in flight
    __builtin_amdgcn_s_barrier();
    __builtin_amdgcn_sched_barrier(0);

    // dist window 0 (s_proto now visible)
    if (nb) {
        float av[8] = {c0.x, c0.y, c0.z, c0.w, c1.x, c1.y, c1.z, c1.w};
        int kb = akc * 8;
        #pragma unroll
        for (int w = 0; w < NWAY; w++) {
            f32x4 pv0 = *(const f32x4*)(s_proto + w * DIM + kb);
            f32x4 pv1 = *(const f32x4*)(s_proto + w * DIM + kb + 4);
            ds[w] += av[0] * pv0[0] + av[1] * pv0[1] + av[2] * pv0[2] + av[3] * pv0[3]
                   + av[4] * pv1[0] + av[5] * pv1[1] + av[6] * pv1[2] + av[7] * pv1[3];
        }
        #pragma unroll
        for (int j = 0; j < 8; j++) qq += av[j] * av[j];
    }

    int slot8 = (hq ^ (r & 3) ^ ((r >> 2) & 1)) * 8;   // swizzled 16B k-slot (shorts)

    for (int it = 0; it < 15; it++) {
        int par = it & 1;
        // issue B(it+1) into other parity
        #pragma unroll
        for (int i = 0; i < 4; i++)
            async16(Bb + (par ^ 1) * 16384 + wv * 4096 + i * 1024,
                    Bg + (size_t)i * 16 * DIM + (it + 1) * 32);
        // issue a(it+2)
        float4 aL0, aL1;
        if (it < 14) {
            aL0 = *(const float4*)(Ag + (it + 2) * 32);
            aL1 = *(const float4*)(Ag + (it + 2) * 32 + 4);
        }
        // stage A(it+1) from aW (loaded one iter ago)
        {
            unsigned int p0 = f2bf(aW0.x) | ((unsigned int)f2bf(aW0.y) << 16);
            unsigned int p1 = f2bf(aW0.z) | ((unsigned int)f2bf(aW0.w) << 16);
            unsigned int p2 = f2bf(aW1.x) | ((unsigned int)f2bf(aW1.y) << 16);
            unsigned int p3 = f2bf(aW1.z) | ((unsigned int)f2bf(aW1.w) << 16);
            *(uint4*)(Ab + (par ^ 1) * 4096 + awoff) = make_uint4(p0, p1, p2, p3);
        }
        // dist window it+1 from the same f32 regs (nb==1 only; round-4 summation order)
        if (nb) {
            float av[8] = {aW0.x, aW0.y, aW0.z, aW0.w, aW1.x, aW1.y, aW1.z, aW1.w};
            int kb = (it + 1) * 32 + akc * 8;
            #pragma unroll
            for (int w = 0; w < NWAY; w++) {
                f32x4 pv0 = *(const f32x4*)(s_proto + w * DIM + kb);
                f32x4 pv1 = *(const f32x4*)(s_proto + w * DIM + kb + 4);
                ds[w] += av[0] * pv0[0] + av[1] * pv0[1] + av[2] * pv0[2] + av[3] * pv0[3]
                       + av[4] * pv1[0] + av[5] * pv1[1] + av[6] * pv1[2] + av[7] * pv1[3];
            }
            #pragma unroll
            for (int j = 0; j < 8; j++) qq += av[j] * av[j];
        }
        // fragments + MFMA on tile it
        const unsigned short* Ap = (const unsigned short*)(Ab + par * 4096);
        const unsigned short* Bp = (const unsigned short*)(Bb + par * 16384);
        bf16x8 af[4], bfr[4];
        #pragma unroll
        for (int mt = 0; mt < 4; mt++)
            af[mt] = *(const bf16x8*)(Ap + (mt * 16 + r) * 32 + slot8);
        #pragma unroll
        for (int nt = 0; nt < 4; nt++)
            bfr[nt] = *(const bf16x8*)(Bp + (wv * 64 + nt * 16 + r) * 32 + slot8);
        #pragma unroll
        for (int mt = 0; mt < 4; mt++)
            #pragma unroll
            for (int nt = 0; nt < 4; nt++)
                acc[mt][nt] = __builtin_amdgcn_mfma_f32_16x16x32_bf16(af[mt], bfr[nt], acc[mt][nt], 0, 0, 0);
        // counted barrier: B(it+1) must land; a(it+2) stays in flight
        if (it < 14) { asm volatile("s_waitcnt lgkmcnt(0) vmcnt(2)" ::: "memory"); }
        else         { asm volatile("s_waitcnt lgkmcnt(0) vmcnt(0)" ::: "memory"); }
        __builtin_amdgcn_s_barrier();
        __builtin_amdgcn_sched_barrier(0);
        if (it < 14) { aW0 = aL0; aW1 = aL1; }
    }
    // final K-step (it = 15, parity 1)
    {
        const unsigned short* Ap = (const unsigned short*)(Ab + 4096);
        const unsigned short* Bp = (const unsigned short*)(Bb + 16384);
        bf16x8 af[4], bfr[4];
        #pragma unroll
        for (int mt = 0; mt < 4; mt++)
            af[mt] = *(const bf16x8*)(Ap + (mt * 16 + r) * 32 + slot8);
        #pragma unroll
        for (int nt = 0; nt < 4; nt++)
            bfr[nt] = *(const bf16x8*)(Bp + (wv * 64 + nt * 16 + r) * 32 + slot8);
        #pragma unroll
        for (int mt = 0; mt < 4; mt++)
            #pragma unroll
            for (int nt = 0; nt < 4; nt++)
                acc[mt][nt] = __builtin_amdgcn_mfma_f32_16x16x32_bf16(af[mt], bfr[nt], acc[mt][nt], 0, 0, 0);
    }
    __syncthreads();   // pipeline LDS dead -> hl reuse safe

    // proto norms (nb==1): wave wv handles ways wv, wv+4 (s_proto stable since prologue)
    if (nb) {
        for (int w = wv; w < NWAY; w += 4) {
            f32x4 a = *(const f32x4*)(s_proto + w * DIM + lane * 8);
            f32x4 b = *(const f32x4*)(s_proto + w * DIM + lane * 8 + 4);
            float ss = a[0]*a[0] + a[1]*a[1] + a[2]*a[2] + a[3]*a[3]
                     + b[0]*b[0] + b[1]*b[1] + b[2]*b[2] + b[3]*b[3];
            #pragma unroll
            for (int off = 32; off > 0; off >>= 1) ss += __shfl_xor(ss, off, 64);
            if (lane == 0) pn_lds[w] = sqrtf(ss);
        }
    }

    // ---- epilogue: bias + relu -> f16 LDS [64][264] ----
    const float* bias = nb ? bc1 : bo1;
    #pragma unroll
    for (int nt = 0; nt < 4; nt++) {
        int cl = wv * 64 + nt * 16 + r;
        float bv = bias[cl];
        #pragma unroll
        for (int mt = 0; mt < 4; mt++)
            #pragma unroll
            for (int rg = 0; rg < 4; rg++) {
                int ml = mt * 16 + hq * 4 + rg;
                hl[ml * 264 + cl] = (_Float16)fmaxf(acc[mt][nt][rg] + bv, 0.0f);
            }
    }
    __syncthreads();   // hl + pn_lds ready

    int q = t & 63, qt = t >> 6;    // qt: 64-col quarter (wave-uniform)
    if (nb == 0) {
        float ox = 0.0f, oy = 0.0f;
        #pragma unroll 2
        for (int j0 = 0; j0 < 64; j0 += 8) {
            half8 hv = *(const half8*)(hl + q * 264 + qt * 64 + j0);
            #pragma unroll
            for (int j = 0; j < 8; j++) {
                float2 w2 = *(const float2*)(Wo2 + (qt * 64 + j0 + j) * 2);
                float hf = (float)hv[j];
                ox += hf * w2.x;
                oy += hf * w2.y;
            }
        }
        redf[(qt * 64 + q) * 2] = ox;
        redf[(qt * 64 + q) * 2 + 1] = oy;
        __syncthreads();
        if (t < 64) {
            float sx = bo2[0], sy = bo2[1];
            #pragma unroll
            for (int k2 = 0; k2 < 4; k2++) {
                sx += redf[(k2 * 64 + t) * 2];
                sy += redf[(k2 * 64 + t) * 2 + 1];
            }
            size_t Q = (size_t)mb * 64 + t;
            float2 icv = *(const float2*)(ic + Q * 2);
            float gx = icv.x / (1.0f + __expf(-sx));
            float gy = icv.y / (1.0f + __expf(-sy));
            float2 g2 = make_float2(gx, gy);
            float2* dst = (float2*)(out_kp + Q * 34);
            #pragma unroll
            for (int k2 = 0; k2 < 17; k2++) dst[k2] = g2;
        }
    } else {
        // dist finalize: reduce over the 4 threads sharing a row (lanes akc 0..3 adjacent)
        #pragma unroll
        for (int off = 1; off <= 2; off <<= 1) {
            #pragma unroll
            for (int w = 0; w < NWAY; w++) ds[w] += __shfl_xor(ds[w], off, 64);
            qq += __shfl_xor(qq, off, 64);
        }
        if (akc == 0) {
            float qn = sqrtf(qq);
            float mv = 1e30f; int ami = 0;
            #pragma unroll
            for (int w = 0; w < NWAY; w++) {
                float den = fmaxf(qn * pn_lds[w], 1e-8f);
                float d = (1.0f - ds[w] / den) * invt;
                dlds[am * 5 + w] = d;
                if (d < mv) { mv = d; ami = w; }
            }
            out_class[mb * 64 + am] = (float)ami;
        }
        // conf-head dot
        float cs = 0.0f;
        #pragma unroll 2
        for (int j0 = 0; j0 < 64; j0 += 8) {
            half8 hv = *(const half8*)(hl + q * 264 + qt * 64 + j0);
            #pragma unroll
            for (int j = 0; j < 8; j++)
                cs += (float)hv[j] * Wc2[qt * 64 + j0 + j];
        }
        redf[qt * 64 + q] = cs;
        __syncthreads();   // redf + dlds ready
        if (t < 64) {
            float s = bc2[0] + redf[t] + redf[64 + t] + redf[128 + t] + redf[192 + t];
            float sg2 = 1.0f / (1.0f + __expf(-s));
            size_t Q = (size_t)mb * 64 + t;
            float* dst = out_conf + Q * 17;
            #pragma unroll
            for (int k2 = 0; k2 < 17; k2++) dst[k2] = sg2;
        }
        // dist out-writes: 64 queries x 85
        for (int i = t; i < 64 * NWAY * NKPTS; i += 256) {
            int q2 = i / (NWAY * NKPTS);
            int rem = i - q2 * (NWAY * NKPTS);
            out_dist[(size_t)(mb * 64 + q2) * (NWAY * NKPTS) + rem] = dlds[q2 * 5 + rem / NKPTS];
        }
    }
}

extern "C" void kernel_launch(void* const* d_in, const int* in_sizes, int n_in,
                              void* d_out, int out_size, void* d_ws, size_t ws_size,
                              hipStream_t stream) {
    const float* sf = (const float*)d_in[0];
    const float* qf = (const float*)d_in[2];
    const float* ic = (const float*)d_in[3];
    const float* W1 = (const float*)d_in[4];
    const float* b1 = (const float*)d_in[5];
    const float* W2 = (const float*)d_in[6];
    const float* b2 = (const float*)d_in[7];
    const float* Wo1 = (const float*)d_in[8];
    const float* bo1 = (const float*)d_in[9];
    const float* Wo2 = (const float*)d_in[10];
    const float* bo2 = (const float*)d_in[11];
    const float* Wc1 = (const float*)d_in[12];
    const float* bc1 = (const float*)d_in[13];
    const float* Wc2 = (const float*)d_in[14];
    const float* bc2 = (const float*)d_in[15];
    const float* temp = (const float*)d_in[16];

    float* out = (float*)d_out;
    float* out_kp = out;                   // 65536*17*2
    float* out_conf = out + 2228224;       // 65536*17
    float* out_dist = out + 3342336;       // 65536*5*17
    float* out_class = out + 8912896;      // 65536
    float* out_proto = out + 8978432;      // 5*17*512

    char* ws = (char*)d_ws;
    float* ws_h1 = (float*)ws;                               // 25*512 f32
    float* ws_proto = (float*)(ws + 51200);                  // 5*512 f32
    unsigned short* ws_wb = (unsigned short*)(ws + 65536);   // 512*512 bf16 (transposed [Wo1|Wc1])

    hipLaunchKernelGGL(k_sup, dim3(200), dim3(256), 0, stream, sf, W1, b1, ws_h1);
    hipLaunchKernelGGL(k_mid2, dim3(104), dim3(256), 0, stream, ws_h1, W2, b2, Wo1, Wc1, ws_proto, ws_wb);
    hipLaunchKernelGGL(k_gemm2, dim3(2048), dim3(256), 0, stream, qf, ws_wb, ws_proto, temp,
                       bo1, Wo2, bo2, bc1, Wc2, bc2, ic, out_kp, out_conf,
                       out_dist, out_class, out_proto);
}